// Round 1
// baseline (252.869 us; speedup 1.0000x reference)
//
#include <hip/hip_runtime.h>
#include <hip/hip_bf16.h>

// Problem constants (from reference)
#define BB 4
#define CC 64
#define NXX 432
#define NYY 496
#define GG (NXX * NYY)          // 214272 cells per batch
#define PP 80000                // total pillars (B * P_PER)

// Key insight: in the reference, prob_buf is zeros and never written (kept bug),
// so p == 0 -> out = spatial exactly. All three linear heads + tanh/relu/sigmoid
// and the propagation scatter-add are dead code. Output is just the dense BEV
// scatter of pillar_features, laid out [B, C, NY, NX].

// Kernel 1: init cell->pillar map to -1 (d_ws is re-poisoned each call)
__global__ void k_init_map(int* __restrict__ map) {
    int i = blockIdx.x * blockDim.x + threadIdx.x;   // one int4 per thread
    const int n4 = (BB * GG) / 4;                    // 214272
    if (i < n4) {
        ((int4*)map)[i] = make_int4(-1, -1, -1, -1);
    }
}

// Kernel 2: scatter pillar ids into the map. Coordinates are unique per batch.
__global__ void k_scatter_ids(const int* __restrict__ coords, int* __restrict__ map) {
    int i = blockIdx.x * blockDim.x + threadIdx.x;
    if (i < PP) {
        int4 cd = ((const int4*)coords)[i];          // (b, z, y, x), z == 0
        int g = cd.x * GG + cd.y + cd.z * NXX + cd.w;
        map[g] = i;
    }
}

// Kernel 3: coalesced gather pass.
// Thread t owns 4 consecutive cells (int4 map read) and 16 channels
// (blockIdx.y selects the 16-channel slice). For each 4-channel group it reads
// one float4 per occupied pillar row (the 4 groups of a slice hit the same
// 64B line -> pf fetched exactly once), transposes in registers, and writes
// float4s that are fully coalesced across the wave.
__global__ void k_gather(const float* __restrict__ pf,
                         const int* __restrict__ map,
                         float* __restrict__ out) {
    int t = blockIdx.x * blockDim.x + threadIdx.x;   // cell-group id (4 cells)
    const int nGroups = (BB * GG) / 4;               // 214272, G%4==0 so groups never cross batches
    if (t >= nGroups) return;

    int cellBase = t * 4;
    int b = cellBase / GG;
    int cellInB = cellBase - b * GG;

    int4 pids = ((const int4*)map)[t];
    const float4* pf4 = (const float4*)pf;           // pf rows are 64 floats = 16 float4s
    const float4 zero = make_float4(0.f, 0.f, 0.f, 0.f);

    float* outBase = out + (size_t)(b * CC) * GG + cellInB;  // 16B-aligned (cellInB%4==0)

    int c0base = blockIdx.y * 16;                    // 16 channels per y-slice

    #pragma unroll
    for (int cg = 0; cg < 4; ++cg) {
        int c0 = c0base + cg * 4;
        int q = c0 >> 2;                             // float4 index within pillar row
        float4 r0 = (pids.x >= 0) ? pf4[pids.x * 16 + q] : zero;
        float4 r1 = (pids.y >= 0) ? pf4[pids.y * 16 + q] : zero;
        float4 r2 = (pids.z >= 0) ? pf4[pids.z * 16 + q] : zero;
        float4 r3 = (pids.w >= 0) ? pf4[pids.w * 16 + q] : zero;

        // transpose: w_k = channel (c0+k) for the 4 cells
        float4 w0 = make_float4(r0.x, r1.x, r2.x, r3.x);
        float4 w1 = make_float4(r0.y, r1.y, r2.y, r3.y);
        float4 w2 = make_float4(r0.z, r1.z, r2.z, r3.z);
        float4 w3 = make_float4(r0.w, r1.w, r2.w, r3.w);

        *((float4*)(outBase + (size_t)(c0 + 0) * GG)) = w0;
        *((float4*)(outBase + (size_t)(c0 + 1) * GG)) = w1;
        *((float4*)(outBase + (size_t)(c0 + 2) * GG)) = w2;
        *((float4*)(outBase + (size_t)(c0 + 3) * GG)) = w3;
    }
}

extern "C" void kernel_launch(void* const* d_in, const int* in_sizes, int n_in,
                              void* d_out, int out_size, void* d_ws, size_t ws_size,
                              hipStream_t stream) {
    const float* pf     = (const float*)d_in[0];     // [80000, 64] f32
    const int*   coords = (const int*)d_in[7];       // [80000, 4] i32 (b,z,y,x)
    float*       out    = (float*)d_out;             // [B, C, NY, NX] f32
    int*         map    = (int*)d_ws;                // [B*G] i32 cell->pillar (needs 3.43 MB)

    const int n4 = (BB * GG) / 4;                    // 214272
    k_init_map<<<dim3((n4 + 255) / 256), dim3(256), 0, stream>>>(map);
    k_scatter_ids<<<dim3((PP + 255) / 256), dim3(256), 0, stream>>>(coords, map);

    const int nGroups = (BB * GG) / 4;               // 214272
    dim3 grid((nGroups + 255) / 256, 4);             // 837 x 4 blocks
    k_gather<<<grid, dim3(256), 0, stream>>>(pf, map, out);
}